// Round 6
// baseline (121.135 us; speedup 1.0000x reference)
//
#include <hip/hip_runtime.h>
#include <math.h>

// Problem constants
#define B_ 8
#define T_ 256
#define A_ 2
#define C_ 128
#define R_ 128
#define H_ 128
#define OUT_ 256

// Workspace layout (float offsets)
#define WS_PCK 0
#define WS_PCV 16384
#define WS_PSK 32768
#define WS_PSV 33792
#define WS_QK  34816
#define WS_W   34944
#define WS_TOTAL 35968  // floats (~144 KB)

// gelu via A&S 7.1.27: erf(z) ~ 1 - (1 + a1 z + a2 z^2 + a3 z^3 + a4 z^4)^-4,
// z >= 0, |err| <= 5e-4, sqrt(1/2) folded into coefficients.
// gelu(x) = max(x,0) - 0.5|x| * q^-4.  9 full-rate VALU + 1 v_rcp, branchless.
__device__ __forceinline__ float gelu_fast(float x) {
    const float ax = fabsf(x);
    float q = fmaf(ax, 0.019527f, 0.000343654f);   // b4, b3
    q = fmaf(q, ax, 0.1151945f);                   // b2
    q = fmaf(q, ax, 0.19685217f);                  // b1
    q = fmaf(q, ax, 1.0f);
    const float r  = __builtin_amdgcn_rcpf(q);
    const float r2 = r * r;
    const float r4 = r2 * r2;
    return fmaf(-0.5f * ax, r4, fmaxf(x, 0.0f));
}

// ---------------------------------------------------------------------------
// Kernel 1: small projection dots into workspace.
// ---------------------------------------------------------------------------
__global__ __launch_bounds__(256) void prep_kernel(
    const float* __restrict__ session,   // [B,H]
    const float* __restrict__ query,     // [R]
    const float* __restrict__ pos,       // [C,R]
    const float* __restrict__ kW1,       // [R+H, R]
    const float* __restrict__ kb1,       // [R]
    const float* __restrict__ kW2,       // [R, R]
    const float* __restrict__ vW1,       // [R+H+1, R]
    const float* __restrict__ vb1,       // [R]
    float* __restrict__ ws)
{
    const int g = blockIdx.x * 256 + threadIdx.x;
    if (g < 16384) {                       // pck[c][r]
        const int c = g >> 7, r = g & 127;
        float acc = 0.0f;
        #pragma unroll 16
        for (int k = 0; k < R_; ++k)
            acc += pos[c * R_ + k] * kW1[k * R_ + r];
        ws[WS_PCK + g] = acc;
    } else if (g < 32768) {                // pcv[c][r]
        const int e = g - 16384;
        const int c = e >> 7, r = e & 127;
        float acc = 0.0f;
        #pragma unroll 16
        for (int k = 0; k < R_; ++k)
            acc += pos[c * R_ + k] * vW1[k * R_ + r];
        ws[WS_PCV + e] = acc;
    } else if (g < 33792) {                // psk[b][r] (+kb1)
        const int e = g - 32768;
        const int b = e >> 7, r = e & 127;
        float acc = kb1[r];
        #pragma unroll 16
        for (int k = 0; k < H_; ++k)
            acc += session[b * H_ + k] * kW1[(R_ + k) * R_ + r];
        ws[WS_PSK + e] = acc;
    } else if (g < 34816) {                // psv[b][r] (+vb1)
        const int e = g - 33792;
        const int b = e >> 7, r = e & 127;
        float acc = vb1[r];
        #pragma unroll 16
        for (int k = 0; k < H_; ++k)
            acc += session[b * H_ + k] * vW1[(R_ + k) * R_ + r];
        ws[WS_PSV + e] = acc;
    } else if (g < 34944) {                // qk[r] = kW2[r,:] . query
        const int r = g - 34816;
        float acc = 0.0f;
        #pragma unroll 16
        for (int j = 0; j < R_; ++j)
            acc += kW2[r * R_ + j] * query[j];
        ws[WS_QK + r] = acc;
    }
}

// ---------------------------------------------------------------------------
// Kernel 2: scores + softmax, wide.  8 blocks x 512 threads.
// ---------------------------------------------------------------------------
__global__ __launch_bounds__(512) void score_softmax_kernel(float* __restrict__ ws)
{
    __shared__ float pskL[R_];
    __shared__ float qkL[R_];
    __shared__ float part[4][C_];
    __shared__ float sc[C_];
    __shared__ float red[C_];

    const int b   = blockIdx.x;
    const int tid = threadIdx.x;
    const int q   = tid >> 7;
    const int c   = tid & 127;

    if (tid < 128) {
        pskL[tid] = ws[WS_PSK + b * R_ + tid];
        qkL[tid]  = ws[WS_QK + tid];
    }
    __syncthreads();

    const float* __restrict__ pckc = ws + WS_PCK + c * R_ + q * 32;
    float acc = 0.0f;
    #pragma unroll 8
    for (int i = 0; i < 32; ++i) {
        const float x = pckc[i] + pskL[q * 32 + i];
        acc += gelu_fast(x) * qkL[q * 32 + i];
    }
    part[q][c] = acc;
    __syncthreads();

    if (tid < 128) {
        const float s = (part[0][tid] + part[1][tid] + part[2][tid] + part[3][tid])
                        * 0.08838834764831845f;  // 1/sqrt(128)
        sc[tid]  = s;
        red[tid] = s;
    }
    __syncthreads();
    for (int st = 64; st > 0; st >>= 1) {
        if (tid < st) red[tid] = fmaxf(red[tid], red[tid + st]);
        __syncthreads();
    }
    const float m = red[0];
    __syncthreads();
    if (tid < 128) {
        const float e = __expf(sc[tid] - m);
        sc[tid]  = e;
        red[tid] = e;
    }
    __syncthreads();
    for (int st = 64; st > 0; st >>= 1) {
        if (tid < st) red[tid] += red[tid + st];
        __syncthreads();
    }
    if (tid < 128) ws[WS_W + b * C_ + tid] = sc[tid] / red[0];
}

// ---------------------------------------------------------------------------
// Kernel 3: main. 1024 blocks x 256 threads; 4 (t,a) rows per block.
// Thread (half = tid>>7, r = tid&127): c in [half*64, +64), 4 gelu chains.
// w[c] and state rows are wave-uniform per c-iter -> read them with uniform
// global addresses so the compiler emits s_load (scalar pipe, K$-batched),
// removing ALL ds_read from the hot loop.  Only LDS use is the 2 KB p4
// half-combine + epilogue broadcast.
// ---------------------------------------------------------------------------
__global__ __launch_bounds__(256) void main_kernel(
    const float* __restrict__ state,  // [B, 512, 128] rows
    const float* __restrict__ vW1,    // [R+H+1, R] ; last row = vrow
    const float* __restrict__ vW2,    // [R, OUT]
    const float* __restrict__ vb2,    // [OUT]
    const float* __restrict__ ws,
    float* __restrict__ out)          // [B, 512, OUT]
{
    __shared__ float4 p4[R_];         // weighted-gelu partials, [r] -> 4 rows

    const int blk  = blockIdx.x;
    const int b    = blk >> 7;        // / 128
    const int grp  = blk & 127;
    const int tid  = threadIdx.x;
    const int r    = tid & 127;
    const int half = tid >> 7;

    const float* __restrict__ srow = state + (size_t)(b * 512 + grp * 4) * C_;
    const float* __restrict__ wb   = ws + WS_W + b * C_;

    const float vr    = vW1[(R_ + H_) * R_ + r];   // vW1 last row, element r
    const float psv_r = ws[WS_PSV + b * R_ + r];

    float acc0 = 0.0f, acc1 = 0.0f, acc2 = 0.0f, acc3 = 0.0f;
    const int c0 = half * 64;
    const float* __restrict__ pcvr = ws + WS_PCV + r;
    #pragma unroll 8
    for (int c = c0; c < c0 + 64; ++c) {
        const float cc = pcvr[c * R_] + psv_r;     // vector load (coalesced)
        const float wc = wb[c];                    // uniform -> s_load
        const float s0 = srow[c];                  // uniform -> s_load
        const float s1 = srow[C_ + c];
        const float s2 = srow[2 * C_ + c];
        const float s3 = srow[3 * C_ + c];
        acc0 = fmaf(wc, gelu_fast(fmaf(s0, vr, cc)), acc0);
        acc1 = fmaf(wc, gelu_fast(fmaf(s1, vr, cc)), acc1);
        acc2 = fmaf(wc, gelu_fast(fmaf(s2, vr, cc)), acc2);
        acc3 = fmaf(wc, gelu_fast(fmaf(s3, vr, cc)), acc3);
    }

    if (half == 0) p4[r] = make_float4(acc0, acc1, acc2, acc3);
    __syncthreads();
    if (half == 1) {
        float4 t = p4[r];
        t.x += acc0; t.y += acc1; t.z += acc2; t.w += acc3;
        p4[r] = t;
    }
    __syncthreads();

    // Epilogue: out[j][h] = p[j,:] @ vW2[:,h] + vb2[h], h = tid
    const int h = tid;
    const float bias = vb2[h];
    float o0 = bias, o1 = bias, o2 = bias, o3 = bias;
    #pragma unroll 16
    for (int rr = 0; rr < R_; ++rr) {
        const float wcol = vW2[rr * OUT_ + h];
        const float4 pr = p4[rr];     // broadcast ds_read_b128
        o0 = fmaf(pr.x, wcol, o0);
        o1 = fmaf(pr.y, wcol, o1);
        o2 = fmaf(pr.z, wcol, o2);
        o3 = fmaf(pr.w, wcol, o3);
    }
    float* __restrict__ orow = out + (size_t)(b * 512 + grp * 4) * OUT_;
    orow[0 * OUT_ + h] = o0;
    orow[1 * OUT_ + h] = o1;
    orow[2 * OUT_ + h] = o2;
    orow[3 * OUT_ + h] = o3;
}

extern "C" void kernel_launch(void* const* d_in, const int* in_sizes, int n_in,
                              void* d_out, int out_size, void* d_ws, size_t ws_size,
                              hipStream_t stream) {
    const float* state   = (const float*)d_in[0];   // [B,T,A,C]
    const float* session = (const float*)d_in[1];   // [B,H]
    const float* query   = (const float*)d_in[4];   // [R]
    const float* pos     = (const float*)d_in[5];   // [C,R]
    const float* kW1     = (const float*)d_in[6];   // [R+H, R]
    const float* kb1     = (const float*)d_in[7];   // [R]
    const float* kW2     = (const float*)d_in[8];   // [R, R]
    const float* vW1     = (const float*)d_in[10];  // [R+H+1, R]
    const float* vb1     = (const float*)d_in[11];  // [R]
    const float* vW2     = (const float*)d_in[12];  // [R, OUT]
    const float* vb2     = (const float*)d_in[13];  // [OUT]

    float* ws  = (float*)d_ws;
    float* out = (float*)d_out;

    prep_kernel<<<137, 256, 0, stream>>>(session, query, pos, kW1, kb1, kW2,
                                         vW1, vb1, ws);
    score_softmax_kernel<<<B_, 512, 0, stream>>>(ws);
    main_kernel<<<B_ * 128, 256, 0, stream>>>(state, vW1, vW2, vb2, ws, out);
}

// Round 7
// 118.138 us; speedup vs baseline: 1.0254x; 1.0254x over previous
//
#include <hip/hip_runtime.h>
#include <math.h>

// Problem constants
#define B_ 8
#define T_ 256
#define A_ 2
#define C_ 128
#define R_ 128
#define H_ 128
#define OUT_ 256

// Workspace layout (float offsets)
#define WS_PCK 0
#define WS_PCV 16384
#define WS_PSK 32768
#define WS_PSV 33792
#define WS_QK  34816
#define WS_W   34944
#define WS_TOTAL 35968  // floats (~144 KB)

// gelu via A&S 7.1.27: erf(z) ~ 1 - (1 + a1 z + a2 z^2 + a3 z^3 + a4 z^4)^-4,
// z >= 0, |err| <= 5e-4, sqrt(1/2) folded into coefficients.
// gelu(x) = max(x,0) - 0.5|x| * q^-4.  9 full-rate VALU + 1 v_rcp, branchless.
__device__ __forceinline__ float gelu_fast(float x) {
    const float ax = fabsf(x);
    float q = fmaf(ax, 0.019527f, 0.000343654f);   // b4, b3
    q = fmaf(q, ax, 0.1151945f);                   // b2
    q = fmaf(q, ax, 0.19685217f);                  // b1
    q = fmaf(q, ax, 1.0f);
    const float r  = __builtin_amdgcn_rcpf(q);
    const float r2 = r * r;
    const float r4 = r2 * r2;
    return fmaf(-0.5f * ax, r4, fmaxf(x, 0.0f));
}

// ---------------------------------------------------------------------------
// Kernel 1: small projection dots into workspace.
// ---------------------------------------------------------------------------
__global__ __launch_bounds__(256) void prep_kernel(
    const float* __restrict__ session,   // [B,H]
    const float* __restrict__ query,     // [R]
    const float* __restrict__ pos,       // [C,R]
    const float* __restrict__ kW1,       // [R+H, R]
    const float* __restrict__ kb1,       // [R]
    const float* __restrict__ kW2,       // [R, R]
    const float* __restrict__ vW1,       // [R+H+1, R]
    const float* __restrict__ vb1,       // [R]
    float* __restrict__ ws)
{
    const int g = blockIdx.x * 256 + threadIdx.x;
    if (g < 16384) {                       // pck[c][r]
        const int c = g >> 7, r = g & 127;
        float acc = 0.0f;
        #pragma unroll 16
        for (int k = 0; k < R_; ++k)
            acc += pos[c * R_ + k] * kW1[k * R_ + r];
        ws[WS_PCK + g] = acc;
    } else if (g < 32768) {                // pcv[c][r]
        const int e = g - 16384;
        const int c = e >> 7, r = e & 127;
        float acc = 0.0f;
        #pragma unroll 16
        for (int k = 0; k < R_; ++k)
            acc += pos[c * R_ + k] * vW1[k * R_ + r];
        ws[WS_PCV + e] = acc;
    } else if (g < 33792) {                // psk[b][r] (+kb1)
        const int e = g - 32768;
        const int b = e >> 7, r = e & 127;
        float acc = kb1[r];
        #pragma unroll 16
        for (int k = 0; k < H_; ++k)
            acc += session[b * H_ + k] * kW1[(R_ + k) * R_ + r];
        ws[WS_PSK + e] = acc;
    } else if (g < 34816) {                // psv[b][r] (+vb1)
        const int e = g - 33792;
        const int b = e >> 7, r = e & 127;
        float acc = vb1[r];
        #pragma unroll 16
        for (int k = 0; k < H_; ++k)
            acc += session[b * H_ + k] * vW1[(R_ + k) * R_ + r];
        ws[WS_PSV + e] = acc;
    } else if (g < 34944) {                // qk[r] = kW2[r,:] . query
        const int r = g - 34816;
        float acc = 0.0f;
        #pragma unroll 16
        for (int j = 0; j < R_; ++j)
            acc += kW2[r * R_ + j] * query[j];
        ws[WS_QK + r] = acc;
    }
}

// ---------------------------------------------------------------------------
// Kernel 2: scores + softmax, wide.  8 blocks x 512 threads.
// ---------------------------------------------------------------------------
__global__ __launch_bounds__(512) void score_softmax_kernel(float* __restrict__ ws)
{
    __shared__ float pskL[R_];
    __shared__ float qkL[R_];
    __shared__ float part[4][C_];
    __shared__ float sc[C_];
    __shared__ float red[C_];

    const int b   = blockIdx.x;
    const int tid = threadIdx.x;
    const int q   = tid >> 7;
    const int c   = tid & 127;

    if (tid < 128) {
        pskL[tid] = ws[WS_PSK + b * R_ + tid];
        qkL[tid]  = ws[WS_QK + tid];
    }
    __syncthreads();

    const float* __restrict__ pckc = ws + WS_PCK + c * R_ + q * 32;
    float acc = 0.0f;
    #pragma unroll 8
    for (int i = 0; i < 32; ++i) {
        const float x = pckc[i] + pskL[q * 32 + i];
        acc += gelu_fast(x) * qkL[q * 32 + i];
    }
    part[q][c] = acc;
    __syncthreads();

    if (tid < 128) {
        const float s = (part[0][tid] + part[1][tid] + part[2][tid] + part[3][tid])
                        * 0.08838834764831845f;  // 1/sqrt(128)
        sc[tid]  = s;
        red[tid] = s;
    }
    __syncthreads();
    for (int st = 64; st > 0; st >>= 1) {
        if (tid < st) red[tid] = fmaxf(red[tid], red[tid + st]);
        __syncthreads();
    }
    const float m = red[0];
    __syncthreads();
    if (tid < 128) {
        const float e = __expf(sc[tid] - m);
        sc[tid]  = e;
        red[tid] = e;
    }
    __syncthreads();
    for (int st = 64; st > 0; st >>= 1) {
        if (tid < st) red[tid] += red[tid + st];
        __syncthreads();
    }
    if (tid < 128) ws[WS_W + b * C_ + tid] = sc[tid] / red[0];
}

// ---------------------------------------------------------------------------
// Kernel 3: main. 2048 blocks x 256 threads; 2 (t,a) rows per block.
// Thread (half = tid>>7, r = tid&127): c in [half*64, +64), 2 gelu chains.
// Hot-loop LDS reads vectorized to ds_read_b128 (float4 over c): LDS pipe
// cost drops 17.4 -> 9 cyc/iter/wave, putting VALU back as the binding pipe
// (R2-R5's VALUBusy~63% was the CU-shared LDS pipe saturating, 3 b32/iter).
// ---------------------------------------------------------------------------
__global__ __launch_bounds__(256) void main_kernel(
    const float* __restrict__ state,  // [B, 512, 128] rows
    const float* __restrict__ vW1,    // [R+H+1, R] ; last row = vrow
    const float* __restrict__ vW2,    // [R, OUT]
    const float* __restrict__ vb2,    // [OUT]
    const float* __restrict__ ws,
    float* __restrict__ out)          // [B, 512, OUT]
{
    __shared__ __align__(16) float sv[2 * C_];   // 2 state rows
    __shared__ __align__(16) float wv[C_];       // softmax weights for this b
    __shared__ float2 p2[R_];                    // partials [r] -> (row0,row1)

    const int blk  = blockIdx.x;
    const int b    = blk >> 8;        // / 256
    const int grp  = blk & 255;
    const int tid  = threadIdx.x;
    const int r    = tid & 127;
    const int half = tid >> 7;

    if (tid < 128) wv[tid] = ws[WS_W + b * C_ + tid];
    const float* __restrict__ srow = state + (size_t)(b * 512 + grp * 2) * C_;
    sv[tid] = srow[tid];              // 256 threads == 2*C_ elements

    const float vr    = vW1[(R_ + H_) * R_ + r];   // vW1 last row, element r
    const float psv_r = ws[WS_PSV + b * R_ + r];
    __syncthreads();

    float acc0 = 0.0f, acc1 = 0.0f;
    const float* __restrict__ pcvr = ws + WS_PCV + r;
    const float4* __restrict__ wv4  = (const float4*)wv;
    const float4* __restrict__ sv04 = (const float4*)sv;
    const float4* __restrict__ sv14 = (const float4*)(sv + C_);

    const int q0 = half * 16;         // c4-group base (16 groups of 4 c's)
    #pragma unroll 4
    for (int c4 = q0; c4 < q0 + 16; ++c4) {
        const float4 w4 = wv4[c4];    // ds_read_b128
        const float4 s0 = sv04[c4];   // ds_read_b128
        const float4 s1 = sv14[c4];   // ds_read_b128
        const int cb = c4 * 4;
        const float cc0 = pcvr[(cb + 0) * R_] + psv_r;   // coalesced VMEM
        const float cc1 = pcvr[(cb + 1) * R_] + psv_r;
        const float cc2 = pcvr[(cb + 2) * R_] + psv_r;
        const float cc3 = pcvr[(cb + 3) * R_] + psv_r;
        acc0 = fmaf(w4.x, gelu_fast(fmaf(s0.x, vr, cc0)), acc0);
        acc1 = fmaf(w4.x, gelu_fast(fmaf(s1.x, vr, cc0)), acc1);
        acc0 = fmaf(w4.y, gelu_fast(fmaf(s0.y, vr, cc1)), acc0);
        acc1 = fmaf(w4.y, gelu_fast(fmaf(s1.y, vr, cc1)), acc1);
        acc0 = fmaf(w4.z, gelu_fast(fmaf(s0.z, vr, cc2)), acc0);
        acc1 = fmaf(w4.z, gelu_fast(fmaf(s1.z, vr, cc2)), acc1);
        acc0 = fmaf(w4.w, gelu_fast(fmaf(s0.w, vr, cc3)), acc0);
        acc1 = fmaf(w4.w, gelu_fast(fmaf(s1.w, vr, cc3)), acc1);
    }

    if (half == 0) p2[r] = make_float2(acc0, acc1);
    __syncthreads();
    if (half == 1) {
        float2 t = p2[r];
        t.x += acc0; t.y += acc1;
        p2[r] = t;
    }
    __syncthreads();

    // Epilogue: out[j][h] = p[j,:] @ vW2[:,h] + vb2[h], h = tid
    const int h = tid;
    const float bias = vb2[h];
    float o0 = bias, o1 = bias;
    #pragma unroll 16
    for (int rr = 0; rr < R_; ++rr) {
        const float wcol = vW2[rr * OUT_ + h];
        const float2 pr = p2[rr];     // one ds_read_b64 broadcast
        o0 = fmaf(pr.x, wcol, o0);
        o1 = fmaf(pr.y, wcol, o1);
    }
    float* __restrict__ orow = out + (size_t)(b * 512 + grp * 2) * OUT_;
    orow[h]        = o0;
    orow[OUT_ + h] = o1;
}

extern "C" void kernel_launch(void* const* d_in, const int* in_sizes, int n_in,
                              void* d_out, int out_size, void* d_ws, size_t ws_size,
                              hipStream_t stream) {
    const float* state   = (const float*)d_in[0];   // [B,T,A,C]
    const float* session = (const float*)d_in[1];   // [B,H]
    const float* query   = (const float*)d_in[4];   // [R]
    const float* pos     = (const float*)d_in[5];   // [C,R]
    const float* kW1     = (const float*)d_in[6];   // [R+H, R]
    const float* kb1     = (const float*)d_in[7];   // [R]
    const float* kW2     = (const float*)d_in[8];   // [R, R]
    const float* vW1     = (const float*)d_in[10];  // [R+H+1, R]
    const float* vb1     = (const float*)d_in[11];  // [R]
    const float* vW2     = (const float*)d_in[12];  // [R, OUT]
    const float* vb2     = (const float*)d_in[13];  // [OUT]

    float* ws  = (float*)d_ws;
    float* out = (float*)d_out;

    prep_kernel<<<137, 256, 0, stream>>>(session, query, pos, kW1, kb1, kW2,
                                         vW1, vb1, ws);
    score_softmax_kernel<<<B_, 512, 0, stream>>>(ws);
    main_kernel<<<B_ * 256, 256, 0, stream>>>(state, vW1, vW2, vb2, ws, out);
}

// Round 8
// 117.491 us; speedup vs baseline: 1.0310x; 1.0055x over previous
//
#include <hip/hip_runtime.h>
#include <math.h>

// Problem constants
#define B_ 8
#define T_ 256
#define A_ 2
#define C_ 128
#define R_ 128
#define H_ 128
#define OUT_ 256

// Workspace layout (float offsets)
#define WS_PCK 0
#define WS_PCV 16384
#define WS_PSK 32768
#define WS_PSV 33792
#define WS_QK  34816
#define WS_W   34944
#define WS_TOTAL 35968  // floats (~144 KB)

// gelu via A&S 7.1.27: erf(z) ~ 1 - (1 + a1 z + a2 z^2 + a3 z^3 + a4 z^4)^-4,
// z >= 0, |err| <= 5e-4, sqrt(1/2) folded into coefficients.
// gelu(x) = max(x,0) - 0.5|x| * q^-4.  9 full-rate VALU + 1 v_rcp, branchless.
__device__ __forceinline__ float gelu_fast(float x) {
    const float ax = fabsf(x);
    float q = fmaf(ax, 0.019527f, 0.000343654f);   // b4, b3
    q = fmaf(q, ax, 0.1151945f);                   // b2
    q = fmaf(q, ax, 0.19685217f);                  // b1
    q = fmaf(q, ax, 1.0f);
    const float r  = __builtin_amdgcn_rcpf(q);
    const float r2 = r * r;
    const float r4 = r2 * r2;
    return fmaf(-0.5f * ax, r4, fmaxf(x, 0.0f));
}

// ---------------------------------------------------------------------------
// Kernel 1: small projection dots into workspace.
// ---------------------------------------------------------------------------
__global__ __launch_bounds__(256) void prep_kernel(
    const float* __restrict__ session,   // [B,H]
    const float* __restrict__ query,     // [R]
    const float* __restrict__ pos,       // [C,R]
    const float* __restrict__ kW1,       // [R+H, R]
    const float* __restrict__ kb1,       // [R]
    const float* __restrict__ kW2,       // [R, R]
    const float* __restrict__ vW1,       // [R+H+1, R]
    const float* __restrict__ vb1,       // [R]
    float* __restrict__ ws)
{
    const int g = blockIdx.x * 256 + threadIdx.x;
    if (g < 16384) {                       // pck[c][r]
        const int c = g >> 7, r = g & 127;
        float acc = 0.0f;
        #pragma unroll 16
        for (int k = 0; k < R_; ++k)
            acc += pos[c * R_ + k] * kW1[k * R_ + r];
        ws[WS_PCK + g] = acc;
    } else if (g < 32768) {                // pcv[c][r]
        const int e = g - 16384;
        const int c = e >> 7, r = e & 127;
        float acc = 0.0f;
        #pragma unroll 16
        for (int k = 0; k < R_; ++k)
            acc += pos[c * R_ + k] * vW1[k * R_ + r];
        ws[WS_PCV + e] = acc;
    } else if (g < 33792) {                // psk[b][r] (+kb1)
        const int e = g - 32768;
        const int b = e >> 7, r = e & 127;
        float acc = kb1[r];
        #pragma unroll 16
        for (int k = 0; k < H_; ++k)
            acc += session[b * H_ + k] * kW1[(R_ + k) * R_ + r];
        ws[WS_PSK + e] = acc;
    } else if (g < 34816) {                // psv[b][r] (+vb1)
        const int e = g - 33792;
        const int b = e >> 7, r = e & 127;
        float acc = vb1[r];
        #pragma unroll 16
        for (int k = 0; k < H_; ++k)
            acc += session[b * H_ + k] * vW1[(R_ + k) * R_ + r];
        ws[WS_PSV + e] = acc;
    } else if (g < 34944) {                // qk[r] = kW2[r,:] . query
        const int r = g - 34816;
        float acc = 0.0f;
        #pragma unroll 16
        for (int j = 0; j < R_; ++j)
            acc += kW2[r * R_ + j] * query[j];
        ws[WS_QK + r] = acc;
    }
}

// ---------------------------------------------------------------------------
// Kernel 2: scores + softmax, wide.  8 blocks x 512 threads.
// ---------------------------------------------------------------------------
__global__ __launch_bounds__(512) void score_softmax_kernel(float* __restrict__ ws)
{
    __shared__ float pskL[R_];
    __shared__ float qkL[R_];
    __shared__ float part[4][C_];
    __shared__ float sc[C_];
    __shared__ float red[C_];

    const int b   = blockIdx.x;
    const int tid = threadIdx.x;
    const int q   = tid >> 7;
    const int c   = tid & 127;

    if (tid < 128) {
        pskL[tid] = ws[WS_PSK + b * R_ + tid];
        qkL[tid]  = ws[WS_QK + tid];
    }
    __syncthreads();

    const float* __restrict__ pckc = ws + WS_PCK + c * R_ + q * 32;
    float acc = 0.0f;
    #pragma unroll 8
    for (int i = 0; i < 32; ++i) {
        const float x = pckc[i] + pskL[q * 32 + i];
        acc += gelu_fast(x) * qkL[q * 32 + i];
    }
    part[q][c] = acc;
    __syncthreads();

    if (tid < 128) {
        const float s = (part[0][tid] + part[1][tid] + part[2][tid] + part[3][tid])
                        * 0.08838834764831845f;  // 1/sqrt(128)
        sc[tid]  = s;
        red[tid] = s;
    }
    __syncthreads();
    for (int st = 64; st > 0; st >>= 1) {
        if (tid < st) red[tid] = fmaxf(red[tid], red[tid + st]);
        __syncthreads();
    }
    const float m = red[0];
    __syncthreads();
    if (tid < 128) {
        const float e = __expf(sc[tid] - m);
        sc[tid]  = e;
        red[tid] = e;
    }
    __syncthreads();
    for (int st = 64; st > 0; st >>= 1) {
        if (tid < st) red[tid] += red[tid + st];
        __syncthreads();
    }
    if (tid < 128) ws[WS_W + b * C_ + tid] = sc[tid] / red[0];
}

// ---------------------------------------------------------------------------
// Kernel 3: main. 1024 blocks x 256 threads; 4 (t,a) rows per block.
// Remap: thread = (r-quad k = tid&31, c-segment seg = tid>>5).  Each thread
// owns r in [4k,4k+4) and 16 c's.  pcv[c][4k..4k+3] is ONE coalesced b128
// per iter (half-wave reads 512B contiguous), c-walk is a +512B immediate
// stride -> hot-loop VMEM instrs drop 4x and the v_lshl_add_u64 address
// chains (the hidden ~40% VALU overhead of R5-R7) mostly vanish.  wv/sv LDS
// reads are half-wave broadcasts.  Segment partials combined via LDS tree.
// ---------------------------------------------------------------------------
__global__ __launch_bounds__(256) void main_kernel(
    const float* __restrict__ state,  // [B, 512, 128] rows
    const float* __restrict__ vW1,    // [R+H+1, R] ; last row = vrow
    const float* __restrict__ vW2,    // [R, OUT]
    const float* __restrict__ vb2,    // [OUT]
    const float* __restrict__ ws,
    float* __restrict__ out)          // [B, 512, OUT]
{
    __shared__ __align__(16) float sv[4 * C_];   // 4 state rows (2 KB)
    __shared__ float wv[C_];                     // softmax weights (0.5 KB)
    __shared__ float4 part[8][R_];               // seg partials (16 KB)
    __shared__ float4 p4[R_];                    // combined partials (2 KB)

    const int blk = blockIdx.x;
    const int b   = blk >> 7;        // / 128
    const int grp = blk & 127;
    const int tid = threadIdx.x;
    const int k   = tid & 31;        // r-quad index: r0 = 4k
    const int seg = tid >> 5;        // c-segment: c in [16*seg, +16)
    const int r0  = k * 4;

    if (tid < 128) wv[tid] = ws[WS_W + b * C_ + tid];
    const float* __restrict__ srow = state + (size_t)(b * 512 + grp * 4) * C_;
    sv[tid]       = srow[tid];
    sv[tid + 256] = srow[tid + 256];

    const float4 vr4  = *(const float4*)(vW1 + (R_ + H_) * R_ + r0);
    const float4 psv4 = *(const float4*)(ws + WS_PSV + b * R_ + r0);
    __syncthreads();

    // acc[row j] -> float4 over the 4 r's
    float4 a0 = make_float4(0.f, 0.f, 0.f, 0.f);
    float4 a1 = a0, a2 = a0, a3 = a0;

    const float* __restrict__ pcvb = ws + WS_PCV + r0;
    const int cbeg = seg * 16;
    #pragma unroll 2
    for (int i = 0; i < 16; ++i) {
        const int c = cbeg + i;
        const float4 pv = *(const float4*)(pcvb + c * R_);  // coalesced b128
        const float cc0 = pv.x + psv4.x;
        const float cc1 = pv.y + psv4.y;
        const float cc2 = pv.z + psv4.z;
        const float cc3 = pv.w + psv4.w;
        const float wc = wv[c];                 // half-wave broadcast
        const float s0 = sv[c];
        const float s1 = sv[C_ + c];
        const float s2 = sv[2 * C_ + c];
        const float s3 = sv[3 * C_ + c];
        a0.x = fmaf(wc, gelu_fast(fmaf(s0, vr4.x, cc0)), a0.x);
        a0.y = fmaf(wc, gelu_fast(fmaf(s0, vr4.y, cc1)), a0.y);
        a0.z = fmaf(wc, gelu_fast(fmaf(s0, vr4.z, cc2)), a0.z);
        a0.w = fmaf(wc, gelu_fast(fmaf(s0, vr4.w, cc3)), a0.w);
        a1.x = fmaf(wc, gelu_fast(fmaf(s1, vr4.x, cc0)), a1.x);
        a1.y = fmaf(wc, gelu_fast(fmaf(s1, vr4.y, cc1)), a1.y);
        a1.z = fmaf(wc, gelu_fast(fmaf(s1, vr4.z, cc2)), a1.z);
        a1.w = fmaf(wc, gelu_fast(fmaf(s1, vr4.w, cc3)), a1.w);
        a2.x = fmaf(wc, gelu_fast(fmaf(s2, vr4.x, cc0)), a2.x);
        a2.y = fmaf(wc, gelu_fast(fmaf(s2, vr4.y, cc1)), a2.y);
        a2.z = fmaf(wc, gelu_fast(fmaf(s2, vr4.z, cc2)), a2.z);
        a2.w = fmaf(wc, gelu_fast(fmaf(s2, vr4.w, cc3)), a2.w);
        a3.x = fmaf(wc, gelu_fast(fmaf(s3, vr4.x, cc0)), a3.x);
        a3.y = fmaf(wc, gelu_fast(fmaf(s3, vr4.y, cc1)), a3.y);
        a3.z = fmaf(wc, gelu_fast(fmaf(s3, vr4.z, cc2)), a3.z);
        a3.w = fmaf(wc, gelu_fast(fmaf(s3, vr4.w, cc3)), a3.w);
    }

    // transpose acc (rows x r) -> part[seg][r] = float4 over rows
    part[seg][r0 + 0] = make_float4(a0.x, a1.x, a2.x, a3.x);
    part[seg][r0 + 1] = make_float4(a0.y, a1.y, a2.y, a3.y);
    part[seg][r0 + 2] = make_float4(a0.z, a1.z, a2.z, a3.z);
    part[seg][r0 + 3] = make_float4(a0.w, a1.w, a2.w, a3.w);
    __syncthreads();

    if (tid < 128) {
        float4 s = part[0][tid];
        #pragma unroll
        for (int sg = 1; sg < 8; ++sg) {
            const float4 t = part[sg][tid];
            s.x += t.x; s.y += t.y; s.z += t.z; s.w += t.w;
        }
        p4[tid] = s;
    }
    __syncthreads();

    // Epilogue: out[j][h] = p[j,:] @ vW2[:,h] + vb2[h], h = tid
    const int h = tid;
    const float bias = vb2[h];
    float o0 = bias, o1 = bias, o2 = bias, o3 = bias;
    #pragma unroll 16
    for (int rr = 0; rr < R_; ++rr) {
        const float wcol = vW2[rr * OUT_ + h];
        const float4 pr = p4[rr];     // broadcast ds_read_b128
        o0 = fmaf(pr.x, wcol, o0);
        o1 = fmaf(pr.y, wcol, o1);
        o2 = fmaf(pr.z, wcol, o2);
        o3 = fmaf(pr.w, wcol, o3);
    }
    float* __restrict__ orow = out + (size_t)(b * 512 + grp * 4) * OUT_;
    orow[0 * OUT_ + h] = o0;
    orow[1 * OUT_ + h] = o1;
    orow[2 * OUT_ + h] = o2;
    orow[3 * OUT_ + h] = o3;
}

extern "C" void kernel_launch(void* const* d_in, const int* in_sizes, int n_in,
                              void* d_out, int out_size, void* d_ws, size_t ws_size,
                              hipStream_t stream) {
    const float* state   = (const float*)d_in[0];   // [B,T,A,C]
    const float* session = (const float*)d_in[1];   // [B,H]
    const float* query   = (const float*)d_in[4];   // [R]
    const float* pos     = (const float*)d_in[5];   // [C,R]
    const float* kW1     = (const float*)d_in[6];   // [R+H, R]
    const float* kb1     = (const float*)d_in[7];   // [R]
    const float* kW2     = (const float*)d_in[8];   // [R, R]
    const float* vW1     = (const float*)d_in[10];  // [R+H+1, R]
    const float* vb1     = (const float*)d_in[11];  // [R]
    const float* vW2     = (const float*)d_in[12];  // [R, OUT]
    const float* vb2     = (const float*)d_in[13];  // [OUT]

    float* ws  = (float*)d_ws;
    float* out = (float*)d_out;

    prep_kernel<<<137, 256, 0, stream>>>(session, query, pos, kW1, kb1, kW2,
                                         vW1, vb1, ws);
    score_softmax_kernel<<<B_, 512, 0, stream>>>(ws);
    main_kernel<<<B_ * 128, 256, 0, stream>>>(state, vW1, vW2, vb2, ws, out);
}

// Round 9
// 115.001 us; speedup vs baseline: 1.0533x; 1.0216x over previous
//
#include <hip/hip_runtime.h>
#include <math.h>

// Problem constants
#define B_ 8
#define T_ 256
#define A_ 2
#define C_ 128
#define R_ 128
#define H_ 128
#define OUT_ 256

// Workspace layout (float offsets)
#define WS_PCK 0
#define WS_PCV 16384
#define WS_PSK 32768
#define WS_PSV 33792
#define WS_QK  34816
#define WS_W   34944
// Taylor-coefficient planes (r-contiguous, [B][C][R]) + S0 [B][R]
#define WS_W1  36864
#define WS_W2  167936
#define WS_W3  299008
#define WS_S0  430080
#define WS_TOTAL 431104  // floats (~1.7 MB)

// gelu via A&S 7.1.27 (|erf err| <= 5e-4), no exp, branchless (scores path).
__device__ __forceinline__ float gelu_fast(float x) {
    const float ax = fabsf(x);
    float q = fmaf(ax, 0.019527f, 0.000343654f);
    q = fmaf(q, ax, 0.1151945f);
    q = fmaf(q, ax, 0.19685217f);
    q = fmaf(q, ax, 1.0f);
    const float r  = __builtin_amdgcn_rcpf(q);
    const float r2 = r * r;
    const float r4 = r2 * r2;
    return fmaf(-0.5f * ax, r4, fmaxf(x, 0.0f));
}

// ---------------------------------------------------------------------------
// Kernel 1: small projection dots into workspace.
// ---------------------------------------------------------------------------
__global__ __launch_bounds__(256) void prep_kernel(
    const float* __restrict__ session,   // [B,H]
    const float* __restrict__ query,     // [R]
    const float* __restrict__ pos,       // [C,R]
    const float* __restrict__ kW1,       // [R+H, R]
    const float* __restrict__ kb1,       // [R]
    const float* __restrict__ kW2,       // [R, R]
    const float* __restrict__ vW1,       // [R+H+1, R]
    const float* __restrict__ vb1,       // [R]
    float* __restrict__ ws)
{
    const int g = blockIdx.x * 256 + threadIdx.x;
    if (g < 16384) {                       // pck[c][r]
        const int c = g >> 7, r = g & 127;
        float acc = 0.0f;
        #pragma unroll 16
        for (int k = 0; k < R_; ++k)
            acc += pos[c * R_ + k] * kW1[k * R_ + r];
        ws[WS_PCK + g] = acc;
    } else if (g < 32768) {                // pcv[c][r]
        const int e = g - 16384;
        const int c = e >> 7, r = e & 127;
        float acc = 0.0f;
        #pragma unroll 16
        for (int k = 0; k < R_; ++k)
            acc += pos[c * R_ + k] * vW1[k * R_ + r];
        ws[WS_PCV + e] = acc;
    } else if (g < 33792) {                // psk[b][r] (+kb1)
        const int e = g - 32768;
        const int b = e >> 7, r = e & 127;
        float acc = kb1[r];
        #pragma unroll 16
        for (int k = 0; k < H_; ++k)
            acc += session[b * H_ + k] * kW1[(R_ + k) * R_ + r];
        ws[WS_PSK + e] = acc;
    } else if (g < 34816) {                // psv[b][r] (+vb1)
        const int e = g - 33792;
        const int b = e >> 7, r = e & 127;
        float acc = vb1[r];
        #pragma unroll 16
        for (int k = 0; k < H_; ++k)
            acc += session[b * H_ + k] * vW1[(R_ + k) * R_ + r];
        ws[WS_PSV + e] = acc;
    } else if (g < 34944) {                // qk[r] = kW2[r,:] . query
        const int r = g - 34816;
        float acc = 0.0f;
        #pragma unroll 16
        for (int j = 0; j < R_; ++j)
            acc += kW2[r * R_ + j] * query[j];
        ws[WS_QK + r] = acc;
    }
}

// ---------------------------------------------------------------------------
// Kernel 2: scores + softmax, wide.  8 blocks x 512 threads.
// ---------------------------------------------------------------------------
__global__ __launch_bounds__(512) void score_softmax_kernel(float* __restrict__ ws)
{
    __shared__ float pskL[R_];
    __shared__ float qkL[R_];
    __shared__ float part[4][C_];
    __shared__ float sc[C_];
    __shared__ float red[C_];

    const int b   = blockIdx.x;
    const int tid = threadIdx.x;
    const int q   = tid >> 7;
    const int c   = tid & 127;

    if (tid < 128) {
        pskL[tid] = ws[WS_PSK + b * R_ + tid];
        qkL[tid]  = ws[WS_QK + tid];
    }
    __syncthreads();

    const float* __restrict__ pckc = ws + WS_PCK + c * R_ + q * 32;
    float acc = 0.0f;
    #pragma unroll 8
    for (int i = 0; i < 32; ++i) {
        const float x = pckc[i] + pskL[q * 32 + i];
        acc += gelu_fast(x) * qkL[q * 32 + i];
    }
    part[q][c] = acc;
    __syncthreads();

    if (tid < 128) {
        const float s = (part[0][tid] + part[1][tid] + part[2][tid] + part[3][tid])
                        * 0.08838834764831845f;  // 1/sqrt(128)
        sc[tid]  = s;
        red[tid] = s;
    }
    __syncthreads();
    for (int st = 64; st > 0; st >>= 1) {
        if (tid < st) red[tid] = fmaxf(red[tid], red[tid + st]);
        __syncthreads();
    }
    const float m = red[0];
    __syncthreads();
    if (tid < 128) {
        const float e = __expf(sc[tid] - m);
        sc[tid]  = e;
        red[tid] = e;
    }
    __syncthreads();
    for (int st = 64; st > 0; st >>= 1) {
        if (tid < st) red[tid] += red[tid + st];
        __syncthreads();
    }
    if (tid < 128) ws[WS_W + b * C_ + tid] = sc[tid] / red[0];
}

// ---------------------------------------------------------------------------
// Kernel 2b: Taylor coefficient planes.  gelu(cc + s*vr) expanded to 3rd
// order around cc; softmax weight w and vr^k folded in:
//   W_k[b,c,r] = w[b,c] * g_k(cc) * vr[r]^k   (k=1..3)
//   S0[b,r]    = sum_c w[b,c] * g0(cc)
// g0=cc*Phi, g1=Phi+cc*phi, g2=phi(2-cc^2)/2, g3=phi*cc*(cc^2-4)/6.
// Remainder <= |g''''|max/24 * (s*vr)^4 <= 0.067*0.29^4 ~ 4.7e-4 per eval.
// 8 blocks x 1024 threads; ~131K evals, trivial cost.
// ---------------------------------------------------------------------------
__global__ __launch_bounds__(1024) void coef_kernel(
    const float* __restrict__ vW1,    // [R+H+1, R]; last row = vr
    float* __restrict__ ws)
{
    __shared__ float red8[8][R_];
    const int b  = blockIdx.x;
    const int t  = threadIdx.x;
    const int r  = t & 127;
    const int cq = t >> 7;

    const float vr  = vW1[(R_ + H_) * R_ + r];
    const float vr2 = vr * vr;
    const float vr3 = vr2 * vr;
    const float psv_r = ws[WS_PSV + b * R_ + r];

    float s0acc = 0.0f;
    #pragma unroll 4
    for (int i = 0; i < 16; ++i) {
        const int c = cq * 16 + i;
        const float cc  = ws[WS_PCV + c * R_ + r] + psv_r;
        const float wgt = ws[WS_W + b * C_ + c];
        // Phi(cc) via A&S 7.1.27 on |cc| (coeffs pre-folded with 1/sqrt2)
        const float ax = fabsf(cc);
        float q = fmaf(ax, 0.019527f, 0.000343654f);
        q = fmaf(q, ax, 0.1151945f);
        q = fmaf(q, ax, 0.19685217f);
        q = fmaf(q, ax, 1.0f);
        const float qi  = __builtin_amdgcn_rcpf(q);
        const float qi2 = qi * qi;
        const float h   = 0.5f * qi2 * qi2;          // = Phi(-|cc|)
        const float Phi = (cc >= 0.0f) ? (1.0f - h) : h;
        const float cc2 = cc * cc;
        const float phi = 0.3989422804f * __expf(-0.5f * cc2);
        const float g0 = cc * Phi;
        const float g1 = fmaf(cc, phi, Phi);
        const float g2 = 0.5f * phi * (2.0f - cc2);
        const float g3 = phi * cc * (cc2 - 4.0f) * (1.0f / 6.0f);
        const size_t idx = (size_t)(b * C_ + c) * R_ + r;
        ws[WS_W1 + idx] = wgt * g1 * vr;
        ws[WS_W2 + idx] = wgt * g2 * vr2;
        ws[WS_W3 + idx] = wgt * g3 * vr3;
        s0acc += wgt * g0;
    }
    red8[cq][r] = s0acc;
    __syncthreads();
    if (t < 128) {
        float s = red8[0][t];
        #pragma unroll
        for (int j = 1; j < 8; ++j) s += red8[j][t];
        ws[WS_S0 + b * R_ + t] = s;
    }
}

// ---------------------------------------------------------------------------
// Kernel 3: main. 1024 blocks x 256 threads; 4 (t,a) rows per block.
// Thread = (r-quad k = tid&31, c-segment seg = tid>>5), 16 c's each.
// Inner loop: 3 coalesced b128 coef loads + cubic-in-s accumulate —
// NO transcendentals, ~3.3x less VALU than the direct-gelu versions
// (which were arithmetic-floor-bound at ~35 us across R5-R8).
// ---------------------------------------------------------------------------
__global__ __launch_bounds__(256) void main_kernel(
    const float* __restrict__ state,  // [B, 512, 128] rows
    const float* __restrict__ vW2,    // [R, OUT]
    const float* __restrict__ vb2,    // [OUT]
    const float* __restrict__ ws,
    float* __restrict__ out)          // [B, 512, OUT]
{
    __shared__ __align__(16) float sv[4 * C_];   // 4 state rows (2 KB)
    __shared__ float4 part[8][R_];               // seg partials (16 KB)
    __shared__ float4 p4[R_];                    // combined partials (2 KB)

    const int blk = blockIdx.x;
    const int b   = blk >> 7;        // / 128
    const int grp = blk & 127;
    const int tid = threadIdx.x;
    const int k   = tid & 31;        // r-quad index: r0 = 4k
    const int seg = tid >> 5;        // c-segment: c in [16*seg, +16)
    const int r0  = k * 4;

    const float* __restrict__ srow = state + (size_t)(b * 512 + grp * 4) * C_;
    sv[tid]       = srow[tid];
    sv[tid + 256] = srow[tid + 256];
    __syncthreads();

    const size_t pbase = (size_t)(b * C_) * R_ + r0;
    const float* __restrict__ W1p = ws + WS_W1 + pbase;
    const float* __restrict__ W2p = ws + WS_W2 + pbase;
    const float* __restrict__ W3p = ws + WS_W3 + pbase;

    float4 a0 = make_float4(0.f, 0.f, 0.f, 0.f);
    float4 a1 = a0, a2 = a0, a3 = a0;

    const int cbeg = seg * 16;
    #pragma unroll 4
    for (int i = 0; i < 16; ++i) {
        const int c = cbeg + i;
        const float4 w1 = *(const float4*)(W1p + (size_t)c * R_);  // b128
        const float4 w2 = *(const float4*)(W2p + (size_t)c * R_);  // b128
        const float4 w3 = *(const float4*)(W3p + (size_t)c * R_);  // b128
        const float sA = sv[c];
        const float sB = sv[C_ + c];
        const float sC = sv[2 * C_ + c];
        const float sD = sv[3 * C_ + c];
        {
            const float s2 = sA * sA, s3 = s2 * sA;
            a0.x = fmaf(w1.x, sA, a0.x); a0.x = fmaf(w2.x, s2, a0.x); a0.x = fmaf(w3.x, s3, a0.x);
            a0.y = fmaf(w1.y, sA, a0.y); a0.y = fmaf(w2.y, s2, a0.y); a0.y = fmaf(w3.y, s3, a0.y);
            a0.z = fmaf(w1.z, sA, a0.z); a0.z = fmaf(w2.z, s2, a0.z); a0.z = fmaf(w3.z, s3, a0.z);
            a0.w = fmaf(w1.w, sA, a0.w); a0.w = fmaf(w2.w, s2, a0.w); a0.w = fmaf(w3.w, s3, a0.w);
        }
        {
            const float s2 = sB * sB, s3 = s2 * sB;
            a1.x = fmaf(w1.x, sB, a1.x); a1.x = fmaf(w2.x, s2, a1.x); a1.x = fmaf(w3.x, s3, a1.x);
            a1.y = fmaf(w1.y, sB, a1.y); a1.y = fmaf(w2.y, s2, a1.y); a1.y = fmaf(w3.y, s3, a1.y);
            a1.z = fmaf(w1.z, sB, a1.z); a1.z = fmaf(w2.z, s2, a1.z); a1.z = fmaf(w3.z, s3, a1.z);
            a1.w = fmaf(w1.w, sB, a1.w); a1.w = fmaf(w2.w, s2, a1.w); a1.w = fmaf(w3.w, s3, a1.w);
        }
        {
            const float s2 = sC * sC, s3 = s2 * sC;
            a2.x = fmaf(w1.x, sC, a2.x); a2.x = fmaf(w2.x, s2, a2.x); a2.x = fmaf(w3.x, s3, a2.x);
            a2.y = fmaf(w1.y, sC, a2.y); a2.y = fmaf(w2.y, s2, a2.y); a2.y = fmaf(w3.y, s3, a2.y);
            a2.z = fmaf(w1.z, sC, a2.z); a2.z = fmaf(w2.z, s2, a2.z); a2.z = fmaf(w3.z, s3, a2.z);
            a2.w = fmaf(w1.w, sC, a2.w); a2.w = fmaf(w2.w, s2, a2.w); a2.w = fmaf(w3.w, s3, a2.w);
        }
        {
            const float s2 = sD * sD, s3 = s2 * sD;
            a3.x = fmaf(w1.x, sD, a3.x); a3.x = fmaf(w2.x, s2, a3.x); a3.x = fmaf(w3.x, s3, a3.x);
            a3.y = fmaf(w1.y, sD, a3.y); a3.y = fmaf(w2.y, s2, a3.y); a3.y = fmaf(w3.y, s3, a3.y);
            a3.z = fmaf(w1.z, sD, a3.z); a3.z = fmaf(w2.z, s2, a3.z); a3.z = fmaf(w3.z, s3, a3.z);
            a3.w = fmaf(w1.w, sD, a3.w); a3.w = fmaf(w2.w, s2, a3.w); a3.w = fmaf(w3.w, s3, a3.w);
        }
    }

    // transpose acc (rows x r) -> part[seg][r] = float4 over rows
    part[seg][r0 + 0] = make_float4(a0.x, a1.x, a2.x, a3.x);
    part[seg][r0 + 1] = make_float4(a0.y, a1.y, a2.y, a3.y);
    part[seg][r0 + 2] = make_float4(a0.z, a1.z, a2.z, a3.z);
    part[seg][r0 + 3] = make_float4(a0.w, a1.w, a2.w, a3.w);
    __syncthreads();

    if (tid < 128) {
        float4 s = part[0][tid];
        #pragma unroll
        for (int sg = 1; sg < 8; ++sg) {
            const float4 t = part[sg][tid];
            s.x += t.x; s.y += t.y; s.z += t.z; s.w += t.w;
        }
        const float s0v = ws[WS_S0 + b * R_ + tid];  // row-independent term
        s.x += s0v; s.y += s0v; s.z += s0v; s.w += s0v;
        p4[tid] = s;
    }
    __syncthreads();

    // Epilogue: out[j][h] = p[j,:] @ vW2[:,h] + vb2[h], h = tid
    const int h = tid;
    const float bias = vb2[h];
    float o0 = bias, o1 = bias, o2 = bias, o3 = bias;
    #pragma unroll 16
    for (int rr = 0; rr < R_; ++rr) {
        const float wcol = vW2[rr * OUT_ + h];
        const float4 pr = p4[rr];     // broadcast ds_read_b128
        o0 = fmaf(pr.x, wcol, o0);
        o1 = fmaf(pr.y, wcol, o1);
        o2 = fmaf(pr.z, wcol, o2);
        o3 = fmaf(pr.w, wcol, o3);
    }
    float* __restrict__ orow = out + (size_t)(b * 512 + grp * 4) * OUT_;
    orow[0 * OUT_ + h] = o0;
    orow[1 * OUT_ + h] = o1;
    orow[2 * OUT_ + h] = o2;
    orow[3 * OUT_ + h] = o3;
}

extern "C" void kernel_launch(void* const* d_in, const int* in_sizes, int n_in,
                              void* d_out, int out_size, void* d_ws, size_t ws_size,
                              hipStream_t stream) {
    const float* state   = (const float*)d_in[0];   // [B,T,A,C]
    const float* session = (const float*)d_in[1];   // [B,H]
    const float* query   = (const float*)d_in[4];   // [R]
    const float* pos     = (const float*)d_in[5];   // [C,R]
    const float* kW1     = (const float*)d_in[6];   // [R+H, R]
    const float* kb1     = (const float*)d_in[7];   // [R]
    const float* kW2     = (const float*)d_in[8];   // [R, R]
    const float* vW1     = (const float*)d_in[10];  // [R+H+1, R]
    const float* vb1     = (const float*)d_in[11];  // [R]
    const float* vW2     = (const float*)d_in[12];  // [R, OUT]
    const float* vb2     = (const float*)d_in[13];  // [OUT]

    float* ws  = (float*)d_ws;
    float* out = (float*)d_out;

    prep_kernel<<<137, 256, 0, stream>>>(session, query, pos, kW1, kb1, kW2,
                                         vW1, vb1, ws);
    score_softmax_kernel<<<B_, 512, 0, stream>>>(ws);
    coef_kernel<<<B_, 1024, 0, stream>>>(vW1, ws);
    main_kernel<<<B_ * 128, 256, 0, stream>>>(state, vW2, vb2, ws, out);
}

// Round 10
// 113.403 us; speedup vs baseline: 1.0682x; 1.0141x over previous
//
#include <hip/hip_runtime.h>
#include <math.h>

// Problem constants
#define B_ 8
#define T_ 256
#define A_ 2
#define C_ 128
#define R_ 128
#define H_ 128
#define OUT_ 256

// Workspace layout (float offsets)
#define WS_PCK 0
#define WS_PCV 16384
#define WS_PSK 32768
#define WS_PSV 33792
#define WS_QK  34816
// Taylor-coefficient planes (r-contiguous, [B][C][R]) + S0 [B][R]
#define WS_W1  36864
#define WS_W2  167936
#define WS_W3  299008
#define WS_S0  430080
#define WS_TOTAL 431104  // floats (~1.7 MB)

// gelu via A&S 7.1.27 (|erf err| <= 5e-4), no exp, branchless (scores path).
__device__ __forceinline__ float gelu_fast(float x) {
    const float ax = fabsf(x);
    float q = fmaf(ax, 0.019527f, 0.000343654f);
    q = fmaf(q, ax, 0.1151945f);
    q = fmaf(q, ax, 0.19685217f);
    q = fmaf(q, ax, 1.0f);
    const float r  = __builtin_amdgcn_rcpf(q);
    const float r2 = r * r;
    const float r4 = r2 * r2;
    return fmaf(-0.5f * ax, r4, fmaxf(x, 0.0f));
}

// ---------------------------------------------------------------------------
// Kernel 1: small projection dots into workspace.
// ---------------------------------------------------------------------------
__global__ __launch_bounds__(256) void prep_kernel(
    const float* __restrict__ session,   // [B,H]
    const float* __restrict__ query,     // [R]
    const float* __restrict__ pos,       // [C,R]
    const float* __restrict__ kW1,       // [R+H, R]
    const float* __restrict__ kb1,       // [R]
    const float* __restrict__ kW2,       // [R, R]
    const float* __restrict__ vW1,       // [R+H+1, R]
    const float* __restrict__ vb1,       // [R]
    float* __restrict__ ws)
{
    const int g = blockIdx.x * 256 + threadIdx.x;
    if (g < 16384) {                       // pck[c][r]
        const int c = g >> 7, r = g & 127;
        float acc = 0.0f;
        #pragma unroll 16
        for (int k = 0; k < R_; ++k)
            acc += pos[c * R_ + k] * kW1[k * R_ + r];
        ws[WS_PCK + g] = acc;
    } else if (g < 32768) {                // pcv[c][r]
        const int e = g - 16384;
        const int c = e >> 7, r = e & 127;
        float acc = 0.0f;
        #pragma unroll 16
        for (int k = 0; k < R_; ++k)
            acc += pos[c * R_ + k] * vW1[k * R_ + r];
        ws[WS_PCV + e] = acc;
    } else if (g < 33792) {                // psk[b][r] (+kb1)
        const int e = g - 32768;
        const int b = e >> 7, r = e & 127;
        float acc = kb1[r];
        #pragma unroll 16
        for (int k = 0; k < H_; ++k)
            acc += session[b * H_ + k] * kW1[(R_ + k) * R_ + r];
        ws[WS_PSK + e] = acc;
    } else if (g < 34816) {                // psv[b][r] (+vb1)
        const int e = g - 33792;
        const int b = e >> 7, r = e & 127;
        float acc = vb1[r];
        #pragma unroll 16
        for (int k = 0; k < H_; ++k)
            acc += session[b * H_ + k] * vW1[(R_ + k) * R_ + r];
        ws[WS_PSV + e] = acc;
    } else if (g < 34944) {                // qk[r] = kW2[r,:] . query
        const int r = g - 34816;
        float acc = 0.0f;
        #pragma unroll 16
        for (int j = 0; j < R_; ++j)
            acc += kW2[r * R_ + j] * query[j];
        ws[WS_QK + r] = acc;
    }
}

// ---------------------------------------------------------------------------
// Kernel 2 (fused): scores + softmax + Taylor coefficient planes.
// 8 blocks x 1024 threads.  Phase 1: scores (thread (q=tid>>7, c=tid&127)
// does a 16-long partial gelu-dot) + in-block softmax -> wL in LDS.
// Phase 2: coefficient planes W1/W2/W3 + S0 (as R9's coef_kernel, wgt
// straight from LDS).  Fusing removes one dispatch + the WS_W round-trip.
// ---------------------------------------------------------------------------
__global__ __launch_bounds__(1024) void softmax_coef_kernel(
    const float* __restrict__ vW1,    // [R+H+1, R]; last row = vr
    float* __restrict__ ws)
{
    __shared__ float pskL[R_];
    __shared__ float qkL[R_];
    __shared__ float part8[8][C_];
    __shared__ float sc[C_];
    __shared__ float red[C_];
    __shared__ float wL[C_];

    const int b   = blockIdx.x;
    const int tid = threadIdx.x;
    const int q   = tid >> 7;        // 0..7
    const int c   = tid & 127;

    if (tid < 128) {
        pskL[tid] = ws[WS_PSK + b * R_ + tid];
        qkL[tid]  = ws[WS_QK + tid];
    }
    __syncthreads();

    // scores: segment q covers r in [16q, 16q+16)
    const float* __restrict__ pckc = ws + WS_PCK + c * R_ + q * 16;
    float acc = 0.0f;
    #pragma unroll
    for (int i = 0; i < 16; ++i) {
        const float x = pckc[i] + pskL[q * 16 + i];
        acc += gelu_fast(x) * qkL[q * 16 + i];
    }
    part8[q][c] = acc;
    __syncthreads();

    if (tid < 128) {
        float s = part8[0][tid];
        #pragma unroll
        for (int j = 1; j < 8; ++j) s += part8[j][tid];
        s *= 0.08838834764831845f;   // 1/sqrt(128)
        sc[tid]  = s;
        red[tid] = s;
    }
    __syncthreads();
    for (int st = 64; st > 0; st >>= 1) {
        if (tid < st) red[tid] = fmaxf(red[tid], red[tid + st]);
        __syncthreads();
    }
    const float m = red[0];
    __syncthreads();
    if (tid < 128) {
        const float e = __expf(sc[tid] - m);
        sc[tid]  = e;
        red[tid] = e;
    }
    __syncthreads();
    for (int st = 64; st > 0; st >>= 1) {
        if (tid < st) red[tid] += red[tid + st];
        __syncthreads();
    }
    if (tid < 128) wL[tid] = sc[tid] / red[0];
    __syncthreads();

    // ---- coef phase: W_k[b,c,r] = w[c]*g_k(cc)*vr^k, S0[b,r] = sum w*g0 ----
    const int r  = c;
    const int cq = q;
    const float vr  = vW1[(R_ + H_) * R_ + r];
    const float vr2 = vr * vr;
    const float vr3 = vr2 * vr;
    const float psv_r = ws[WS_PSV + b * R_ + r];

    float s0acc = 0.0f;
    #pragma unroll 4
    for (int i = 0; i < 16; ++i) {
        const int c2 = cq * 16 + i;
        const float cc  = ws[WS_PCV + c2 * R_ + r] + psv_r;
        const float wgt = wL[c2];
        // Phi(cc) via A&S 7.1.27 on |cc| (coeffs pre-folded with 1/sqrt2)
        const float ax = fabsf(cc);
        float qq = fmaf(ax, 0.019527f, 0.000343654f);
        qq = fmaf(qq, ax, 0.1151945f);
        qq = fmaf(qq, ax, 0.19685217f);
        qq = fmaf(qq, ax, 1.0f);
        const float qi  = __builtin_amdgcn_rcpf(qq);
        const float qi2 = qi * qi;
        const float h   = 0.5f * qi2 * qi2;          // = Phi(-|cc|)
        const float Phi = (cc >= 0.0f) ? (1.0f - h) : h;
        const float cc2 = cc * cc;
        const float phi = 0.3989422804f * __expf(-0.5f * cc2);
        const float g0 = cc * Phi;
        const float g1 = fmaf(cc, phi, Phi);
        const float g2 = 0.5f * phi * (2.0f - cc2);
        const float g3 = phi * cc * (cc2 - 4.0f) * (1.0f / 6.0f);
        const size_t idx = (size_t)(b * C_ + c2) * R_ + r;
        ws[WS_W1 + idx] = wgt * g1 * vr;
        ws[WS_W2 + idx] = wgt * g2 * vr2;
        ws[WS_W3 + idx] = wgt * g3 * vr3;
        s0acc += wgt * g0;
    }
    part8[cq][r] = s0acc;            // reuse part8 for the S0 reduction
    __syncthreads();
    if (tid < 128) {
        float s = part8[0][tid];
        #pragma unroll
        for (int j = 1; j < 8; ++j) s += part8[j][tid];
        ws[WS_S0 + b * R_ + tid] = s;
    }
}

// ---------------------------------------------------------------------------
// Kernel 3: main. 1024 blocks x 256 threads; 4 (t,a) rows per block.
// Loop identical to R9 (cubic-in-s, no transcendentals).  Epilogue rebuilt
// as split-K register-tiled GEMM: thread (hq=tid&63, kq=tid>>6) computes a
// 4-row x 4-h tile over rr in [32kq,+32) -> p4 LDS broadcasts drop 128->32
// b128/lane (the hidden ~10us/CU LDS-pipe cost of R5-R9), vW2 and stores
// become b128.  kq-partials combine via LDS aliased onto the dead part[].
// ---------------------------------------------------------------------------
__global__ __launch_bounds__(256) void main_kernel(
    const float* __restrict__ state,  // [B, 512, 128] rows
    const float* __restrict__ vW2,    // [R, OUT]
    const float* __restrict__ vb2,    // [OUT]
    const float* __restrict__ ws,
    float* __restrict__ out)          // [B, 512, OUT]
{
    __shared__ __align__(16) float sv[4 * C_];   // 4 state rows (2 KB)
    __shared__ float4 part[8][R_];               // seg partials (16 KB), reused as ep
    __shared__ float4 p4[R_];                    // combined partials (2 KB)

    const int blk = blockIdx.x;
    const int b   = blk >> 7;        // / 128
    const int grp = blk & 127;
    const int tid = threadIdx.x;
    const int k   = tid & 31;        // r-quad index: r0 = 4k
    const int seg = tid >> 5;        // c-segment: c in [16*seg, +16)
    const int r0  = k * 4;

    const float* __restrict__ srow = state + (size_t)(b * 512 + grp * 4) * C_;
    sv[tid]       = srow[tid];
    sv[tid + 256] = srow[tid + 256];
    __syncthreads();

    const size_t pbase = (size_t)(b * C_) * R_ + r0;
    const float* __restrict__ W1p = ws + WS_W1 + pbase;
    const float* __restrict__ W2p = ws + WS_W2 + pbase;
    const float* __restrict__ W3p = ws + WS_W3 + pbase;

    float4 a0 = make_float4(0.f, 0.f, 0.f, 0.f);
    float4 a1 = a0, a2 = a0, a3 = a0;

    const int cbeg = seg * 16;
    #pragma unroll 4
    for (int i = 0; i < 16; ++i) {
        const int c = cbeg + i;
        const float4 w1 = *(const float4*)(W1p + (size_t)c * R_);  // b128
        const float4 w2 = *(const float4*)(W2p + (size_t)c * R_);  // b128
        const float4 w3 = *(const float4*)(W3p + (size_t)c * R_);  // b128
        const float sA = sv[c];
        const float sB = sv[C_ + c];
        const float sC = sv[2 * C_ + c];
        const float sD = sv[3 * C_ + c];
        {
            const float s2 = sA * sA, s3 = s2 * sA;
            a0.x = fmaf(w1.x, sA, a0.x); a0.x = fmaf(w2.x, s2, a0.x); a0.x = fmaf(w3.x, s3, a0.x);
            a0.y = fmaf(w1.y, sA, a0.y); a0.y = fmaf(w2.y, s2, a0.y); a0.y = fmaf(w3.y, s3, a0.y);
            a0.z = fmaf(w1.z, sA, a0.z); a0.z = fmaf(w2.z, s2, a0.z); a0.z = fmaf(w3.z, s3, a0.z);
            a0.w = fmaf(w1.w, sA, a0.w); a0.w = fmaf(w2.w, s2, a0.w); a0.w = fmaf(w3.w, s3, a0.w);
        }
        {
            const float s2 = sB * sB, s3 = s2 * sB;
            a1.x = fmaf(w1.x, sB, a1.x); a1.x = fmaf(w2.x, s2, a1.x); a1.x = fmaf(w3.x, s3, a1.x);
            a1.y = fmaf(w1.y, sB, a1.y); a1.y = fmaf(w2.y, s2, a1.y); a1.y = fmaf(w3.y, s3, a1.y);
            a1.z = fmaf(w1.z, sB, a1.z); a1.z = fmaf(w2.z, s2, a1.z); a1.z = fmaf(w3.z, s3, a1.z);
            a1.w = fmaf(w1.w, sB, a1.w); a1.w = fmaf(w2.w, s2, a1.w); a1.w = fmaf(w3.w, s3, a1.w);
        }
        {
            const float s2 = sC * sC, s3 = s2 * sC;
            a2.x = fmaf(w1.x, sC, a2.x); a2.x = fmaf(w2.x, s2, a2.x); a2.x = fmaf(w3.x, s3, a2.x);
            a2.y = fmaf(w1.y, sC, a2.y); a2.y = fmaf(w2.y, s2, a2.y); a2.y = fmaf(w3.y, s3, a2.y);
            a2.z = fmaf(w1.z, sC, a2.z); a2.z = fmaf(w2.z, s2, a2.z); a2.z = fmaf(w3.z, s3, a2.z);
            a2.w = fmaf(w1.w, sC, a2.w); a2.w = fmaf(w2.w, s2, a2.w); a2.w = fmaf(w3.w, s3, a2.w);
        }
        {
            const float s2 = sD * sD, s3 = s2 * sD;
            a3.x = fmaf(w1.x, sD, a3.x); a3.x = fmaf(w2.x, s2, a3.x); a3.x = fmaf(w3.x, s3, a3.x);
            a3.y = fmaf(w1.y, sD, a3.y); a3.y = fmaf(w2.y, s2, a3.y); a3.y = fmaf(w3.y, s3, a3.y);
            a3.z = fmaf(w1.z, sD, a3.z); a3.z = fmaf(w2.z, s2, a3.z); a3.z = fmaf(w3.z, s3, a3.z);
            a3.w = fmaf(w1.w, sD, a3.w); a3.w = fmaf(w2.w, s2, a3.w); a3.w = fmaf(w3.w, s3, a3.w);
        }
    }

    // transpose acc (rows x r) -> part[seg][r] = float4 over rows
    part[seg][r0 + 0] = make_float4(a0.x, a1.x, a2.x, a3.x);
    part[seg][r0 + 1] = make_float4(a0.y, a1.y, a2.y, a3.y);
    part[seg][r0 + 2] = make_float4(a0.z, a1.z, a2.z, a3.z);
    part[seg][r0 + 3] = make_float4(a0.w, a1.w, a2.w, a3.w);
    __syncthreads();

    if (tid < 128) {
        float4 s = part[0][tid];
        #pragma unroll
        for (int sg = 1; sg < 8; ++sg) {
            const float4 t = part[sg][tid];
            s.x += t.x; s.y += t.y; s.z += t.z; s.w += t.w;
        }
        const float s0v = ws[WS_S0 + b * R_ + tid];  // row-independent term
        s.x += s0v; s.y += s0v; s.z += s0v; s.w += s0v;
        p4[tid] = s;
    }
    __syncthreads();   // part[] is dead from here; reuse its LDS for ep[]

    // Epilogue v2: split-K register-tiled GEMM.
    // thread = (hq = tid&63 -> h0 = 4*hq, kq = tid>>6 -> rr in [32kq,+32))
    float4 (*ep)[4][64] = (float4 (*)[4][64])part;   // [kq][row][hq], 16 KB
    const int hq = tid & 63;
    const int kq = tid >> 6;
    const int h0 = hq * 4;

    float4 o0 = make_float4(0.f, 0.f, 0.f, 0.f);
    float4 o1 = o0, o2 = o0, o3 = o0;
    const int rrb = kq * 32;
    #pragma unroll 8
    for (int i = 0; i < 32; ++i) {
        const int rr = rrb + i;
        const float4 pr  = p4[rr];                                // b128 broadcast
        const float4 wv4 = *(const float4*)(vW2 + rr * OUT_ + h0); // b128 coalesced
        o0.x = fmaf(pr.x, wv4.x, o0.x); o0.y = fmaf(pr.x, wv4.y, o0.y);
        o0.z = fmaf(pr.x, wv4.z, o0.z); o0.w = fmaf(pr.x, wv4.w, o0.w);
        o1.x = fmaf(pr.y, wv4.x, o1.x); o1.y = fmaf(pr.y, wv4.y, o1.y);
        o1.z = fmaf(pr.y, wv4.z, o1.z); o1.w = fmaf(pr.y, wv4.w, o1.w);
        o2.x = fmaf(pr.z, wv4.x, o2.x); o2.y = fmaf(pr.z, wv4.y, o2.y);
        o2.z = fmaf(pr.z, wv4.z, o2.z); o2.w = fmaf(pr.z, wv4.w, o2.w);
        o3.x = fmaf(pr.w, wv4.x, o3.x); o3.y = fmaf(pr.w, wv4.y, o3.y);
        o3.z = fmaf(pr.w, wv4.z, o3.z); o3.w = fmaf(pr.w, wv4.w, o3.w);
    }
    ep[kq][0][hq] = o0;
    ep[kq][1][hq] = o1;
    ep[kq][2][hq] = o2;
    ep[kq][3][hq] = o3;
    __syncthreads();

    // final combine: thread = (row = tid>>6, hq = tid&63)
    const int row = tid >> 6;
    const float4 e0 = ep[0][row][hq];
    const float4 e1 = ep[1][row][hq];
    const float4 e2 = ep[2][row][hq];
    const float4 e3 = ep[3][row][hq];
    const float4 bias = *(const float4*)(vb2 + h0);
    float4 o;
    o.x = e0.x + e1.x + e2.x + e3.x + bias.x;
    o.y = e0.y + e1.y + e2.y + e3.y + bias.y;
    o.z = e0.z + e1.z + e2.z + e3.z + bias.z;
    o.w = e0.w + e1.w + e2.w + e3.w + bias.w;
    float* __restrict__ orow = out + (size_t)(b * 512 + grp * 4) * OUT_;
    *(float4*)(orow + row * OUT_ + h0) = o;    // b128 coalesced store
}

extern "C" void kernel_launch(void* const* d_in, const int* in_sizes, int n_in,
                              void* d_out, int out_size, void* d_ws, size_t ws_size,
                              hipStream_t stream) {
    const float* state   = (const float*)d_in[0];   // [B,T,A,C]
    const float* session = (const float*)d_in[1];   // [B,H]
    const float* query   = (const float*)d_in[4];   // [R]
    const float* pos     = (const float*)d_in[5];   // [C,R]
    const float* kW1     = (const float*)d_in[6];   // [R+H, R]
    const float* kb1     = (const float*)d_in[7];   // [R]
    const float* kW2     = (const float*)d_in[8];   // [R, R]
    const float* vW1     = (const float*)d_in[10];  // [R+H+1, R]
    const float* vb1     = (const float*)d_in[11];  // [R]
    const float* vW2     = (const float*)d_in[12];  // [R, OUT]
    const float* vb2     = (const float*)d_in[13];  // [OUT]

    float* ws  = (float*)d_ws;
    float* out = (float*)d_out;

    prep_kernel<<<137, 256, 0, stream>>>(session, query, pos, kW1, kb1, kW2,
                                         vW1, vb1, ws);
    softmax_coef_kernel<<<B_, 1024, 0, stream>>>(vW1, ws);
    main_kernel<<<B_ * 128, 256, 0, stream>>>(state, vW2, vb2, ws, out);
}

// Round 12
// 108.722 us; speedup vs baseline: 1.1142x; 1.0430x over previous
//
#include <hip/hip_runtime.h>
#include <math.h>

// Problem constants
#define B_ 8
#define T_ 256
#define A_ 2
#define C_ 128
#define R_ 128
#define H_ 128
#define OUT_ 256

// Workspace layout (float offsets)
#define WS_PCK 0
#define WS_PCV 16384
#define WS_PSK 32768
#define WS_PSV 33792
#define WS_QK  34816
// Taylor-coefficient planes (r-contiguous, [B][C][R]) + S0 [B][R]
#define WS_W1  36864
#define WS_W2  167936
#define WS_W3  299008
#define WS_S0  430080
#define WS_TOTAL 431104  // floats (~1.7 MB)

// gelu via A&S 7.1.27 (|erf err| <= 5e-4), no exp, branchless (scores path).
__device__ __forceinline__ float gelu_fast(float x) {
    const float ax = fabsf(x);
    float q = fmaf(ax, 0.019527f, 0.000343654f);
    q = fmaf(q, ax, 0.1151945f);
    q = fmaf(q, ax, 0.19685217f);
    q = fmaf(q, ax, 1.0f);
    const float r  = __builtin_amdgcn_rcpf(q);
    const float r2 = r * r;
    const float r4 = r2 * r2;
    return fmaf(-0.5f * ax, r4, fmaxf(x, 0.0f));
}

// ---------------------------------------------------------------------------
// Kernel 1: small projection dots into workspace.
// ---------------------------------------------------------------------------
__global__ __launch_bounds__(256) void prep_kernel(
    const float* __restrict__ session,   // [B,H]
    const float* __restrict__ query,     // [R]
    const float* __restrict__ pos,       // [C,R]
    const float* __restrict__ kW1,       // [R+H, R]
    const float* __restrict__ kb1,       // [R]
    const float* __restrict__ kW2,       // [R, R]
    const float* __restrict__ vW1,       // [R+H+1, R]
    const float* __restrict__ vb1,       // [R]
    float* __restrict__ ws)
{
    const int g = blockIdx.x * 256 + threadIdx.x;
    if (g < 16384) {                       // pck[c][r]
        const int c = g >> 7, r = g & 127;
        float acc = 0.0f;
        #pragma unroll 16
        for (int k = 0; k < R_; ++k)
            acc += pos[c * R_ + k] * kW1[k * R_ + r];
        ws[WS_PCK + g] = acc;
    } else if (g < 32768) {                // pcv[c][r]
        const int e = g - 16384;
        const int c = e >> 7, r = e & 127;
        float acc = 0.0f;
        #pragma unroll 16
        for (int k = 0; k < R_; ++k)
            acc += pos[c * R_ + k] * vW1[k * R_ + r];
        ws[WS_PCV + e] = acc;
    } else if (g < 33792) {                // psk[b][r] (+kb1)
        const int e = g - 32768;
        const int b = e >> 7, r = e & 127;
        float acc = kb1[r];
        #pragma unroll 16
        for (int k = 0; k < H_; ++k)
            acc += session[b * H_ + k] * kW1[(R_ + k) * R_ + r];
        ws[WS_PSK + e] = acc;
    } else if (g < 34816) {                // psv[b][r] (+vb1)
        const int e = g - 33792;
        const int b = e >> 7, r = e & 127;
        float acc = vb1[r];
        #pragma unroll 16
        for (int k = 0; k < H_; ++k)
            acc += session[b * H_ + k] * vW1[(R_ + k) * R_ + r];
        ws[WS_PSV + e] = acc;
    } else if (g < 34944) {                // qk[r] = kW2[r,:] . query
        const int r = g - 34816;
        float acc = 0.0f;
        #pragma unroll 16
        for (int j = 0; j < R_; ++j)
            acc += kW2[r * R_ + j] * query[j];
        ws[WS_QK + r] = acc;
    }
}

// ---------------------------------------------------------------------------
// Kernel 2 (fused): scores + softmax + Taylor coefficient planes.
// 8 blocks x 1024 threads.
// ---------------------------------------------------------------------------
__global__ __launch_bounds__(1024) void softmax_coef_kernel(
    const float* __restrict__ vW1,    // [R+H+1, R]; last row = vr
    float* __restrict__ ws)
{
    __shared__ float pskL[R_];
    __shared__ float qkL[R_];
    __shared__ float part8[8][C_];
    __shared__ float sc[C_];
    __shared__ float red[C_];
    __shared__ float wL[C_];

    const int b   = blockIdx.x;
    const int tid = threadIdx.x;
    const int q   = tid >> 7;        // 0..7
    const int c   = tid & 127;

    if (tid < 128) {
        pskL[tid] = ws[WS_PSK + b * R_ + tid];
        qkL[tid]  = ws[WS_QK + tid];
    }
    __syncthreads();

    // scores: segment q covers r in [16q, 16q+16)
    const float* __restrict__ pckc = ws + WS_PCK + c * R_ + q * 16;
    float acc = 0.0f;
    #pragma unroll
    for (int i = 0; i < 16; ++i) {
        const float x = pckc[i] + pskL[q * 16 + i];
        acc += gelu_fast(x) * qkL[q * 16 + i];
    }
    part8[q][c] = acc;
    __syncthreads();

    if (tid < 128) {
        float s = part8[0][tid];
        #pragma unroll
        for (int j = 1; j < 8; ++j) s += part8[j][tid];
        s *= 0.08838834764831845f;   // 1/sqrt(128)
        sc[tid]  = s;
        red[tid] = s;
    }
    __syncthreads();
    for (int st = 64; st > 0; st >>= 1) {
        if (tid < st) red[tid] = fmaxf(red[tid], red[tid + st]);
        __syncthreads();
    }
    const float m = red[0];
    __syncthreads();
    if (tid < 128) {
        const float e = __expf(sc[tid] - m);
        sc[tid]  = e;
        red[tid] = e;
    }
    __syncthreads();
    for (int st = 64; st > 0; st >>= 1) {
        if (tid < st) red[tid] += red[tid + st];
        __syncthreads();
    }
    if (tid < 128) wL[tid] = sc[tid] / red[0];
    __syncthreads();

    // ---- coef phase: W_k[b,c,r] = w[c]*g_k(cc)*vr^k, S0[b,r] = sum w*g0 ----
    const int r  = c;
    const int cq = q;
    const float vr  = vW1[(R_ + H_) * R_ + r];
    const float vr2 = vr * vr;
    const float vr3 = vr2 * vr;
    const float psv_r = ws[WS_PSV + b * R_ + r];

    float s0acc = 0.0f;
    #pragma unroll 4
    for (int i = 0; i < 16; ++i) {
        const int c2 = cq * 16 + i;
        const float cc  = ws[WS_PCV + c2 * R_ + r] + psv_r;
        const float wgt = wL[c2];
        // Phi(cc) via A&S 7.1.27 on |cc| (coeffs pre-folded with 1/sqrt2)
        const float ax = fabsf(cc);
        float qq = fmaf(ax, 0.019527f, 0.000343654f);
        qq = fmaf(qq, ax, 0.1151945f);
        qq = fmaf(qq, ax, 0.19685217f);
        qq = fmaf(qq, ax, 1.0f);
        const float qi  = __builtin_amdgcn_rcpf(qq);
        const float qi2 = qi * qi;
        const float h   = 0.5f * qi2 * qi2;          // = Phi(-|cc|)
        const float Phi = (cc >= 0.0f) ? (1.0f - h) : h;
        const float cc2 = cc * cc;
        const float phi = 0.3989422804f * __expf(-0.5f * cc2);
        const float g0 = cc * Phi;
        const float g1 = fmaf(cc, phi, Phi);
        const float g2 = 0.5f * phi * (2.0f - cc2);
        const float g3 = phi * cc * (cc2 - 4.0f) * (1.0f / 6.0f);
        const size_t idx = (size_t)(b * C_ + c2) * R_ + r;
        ws[WS_W1 + idx] = wgt * g1 * vr;
        ws[WS_W2 + idx] = wgt * g2 * vr2;
        ws[WS_W3 + idx] = wgt * g3 * vr3;
        s0acc += wgt * g0;
    }
    part8[cq][r] = s0acc;            // reuse part8 for the S0 reduction
    __syncthreads();
    if (tid < 128) {
        float s = part8[0][tid];
        #pragma unroll
        for (int j = 1; j < 8; ++j) s += part8[j][tid];
        ws[WS_S0 + b * R_ + tid] = s;
    }
}

// ---------------------------------------------------------------------------
// Kernel 3: main. 512 blocks x 256 threads; EIGHT (t,a) rows per block.
// Halves every per-output traffic stream vs R10 (coef planes 201->100 MB,
// vW2 134->67 MB, epilogue LDS per output /2) while hot-loop VMEM stays
// 3 b128 per c-iter -> arithmetic intensity doubles toward the VALU floor.
// ---------------------------------------------------------------------------
__global__ __launch_bounds__(256) void main_kernel(
    const float* __restrict__ state,  // [B, 512, 128] rows
    const float* __restrict__ vW2,    // [R, OUT]
    const float* __restrict__ vb2,    // [OUT]
    const float* __restrict__ ws,
    float* __restrict__ out)          // [B, 512, OUT]
{
    __shared__ __align__(16) float sv[8 * C_];    // 8 state rows (4 KB)
    __shared__ float4 smem[2][8][R_];             // 32 KB: transpose partials,
                                                  // then reused as ep[4][8][64]
    __shared__ float4 p4lo[R_];                   // combined partials rows 0-3
    __shared__ float4 p4hi[R_];                   // combined partials rows 4-7

    const int blk = blockIdx.x;
    const int b   = blk >> 6;        // / 64
    const int grp = blk & 63;
    const int tid = threadIdx.x;
    const int k   = tid & 31;        // r-quad index: r0 = 4k
    const int seg = tid >> 5;        // c-segment: c in [16*seg, +16)
    const int r0  = k * 4;

    const float* __restrict__ srow = state + (size_t)(b * 512 + grp * 8) * C_;
    #pragma unroll
    for (int i = 0; i < 4; ++i) sv[tid + 256 * i] = srow[tid + 256 * i];
    __syncthreads();

    const size_t pbase = (size_t)(b * C_) * R_ + r0;
    const float* __restrict__ W1p = ws + WS_W1 + pbase;
    const float* __restrict__ W2p = ws + WS_W2 + pbase;
    const float* __restrict__ W3p = ws + WS_W3 + pbase;

    float4 a[8];
    #pragma unroll
    for (int j = 0; j < 8; ++j) a[j] = make_float4(0.f, 0.f, 0.f, 0.f);

    const int cbeg = seg * 16;
    #pragma unroll 2
    for (int i = 0; i < 16; ++i) {
        const int c = cbeg + i;
        const float4 w1 = *(const float4*)(W1p + (size_t)c * R_);  // b128
        const float4 w2 = *(const float4*)(W2p + (size_t)c * R_);  // b128
        const float4 w3 = *(const float4*)(W3p + (size_t)c * R_);  // b128
        #pragma unroll
        for (int j = 0; j < 8; ++j) {
            const float s  = sv[j * C_ + c];
            const float s2 = s * s;
            const float s3 = s2 * s;
            a[j].x = fmaf(w1.x, s, a[j].x); a[j].x = fmaf(w2.x, s2, a[j].x); a[j].x = fmaf(w3.x, s3, a[j].x);
            a[j].y = fmaf(w1.y, s, a[j].y); a[j].y = fmaf(w2.y, s2, a[j].y); a[j].y = fmaf(w3.y, s3, a[j].y);
            a[j].z = fmaf(w1.z, s, a[j].z); a[j].z = fmaf(w2.z, s2, a[j].z); a[j].z = fmaf(w3.z, s3, a[j].z);
            a[j].w = fmaf(w1.w, s, a[j].w); a[j].w = fmaf(w2.w, s2, a[j].w); a[j].w = fmaf(w3.w, s3, a[j].w);
        }
    }

    // transpose: smem[0][seg][r] = rows0-3 partials, smem[1][seg][r] = rows4-7
    smem[0][seg][r0 + 0] = make_float4(a[0].x, a[1].x, a[2].x, a[3].x);
    smem[0][seg][r0 + 1] = make_float4(a[0].y, a[1].y, a[2].y, a[3].y);
    smem[0][seg][r0 + 2] = make_float4(a[0].z, a[1].z, a[2].z, a[3].z);
    smem[0][seg][r0 + 3] = make_float4(a[0].w, a[1].w, a[2].w, a[3].w);
    smem[1][seg][r0 + 0] = make_float4(a[4].x, a[5].x, a[6].x, a[7].x);
    smem[1][seg][r0 + 1] = make_float4(a[4].y, a[5].y, a[6].y, a[7].y);
    smem[1][seg][r0 + 2] = make_float4(a[4].z, a[5].z, a[6].z, a[7].z);
    smem[1][seg][r0 + 3] = make_float4(a[4].w, a[5].w, a[6].w, a[7].w);
    __syncthreads();

    if (tid < 128) {
        float4 lo = smem[0][0][tid];
        float4 hi = smem[1][0][tid];
        #pragma unroll
        for (int sg = 1; sg < 8; ++sg) {
            const float4 tl = smem[0][sg][tid];
            const float4 th = smem[1][sg][tid];
            lo.x += tl.x; lo.y += tl.y; lo.z += tl.z; lo.w += tl.w;
            hi.x += th.x; hi.y += th.y; hi.z += th.z; hi.w += th.w;
        }
        const float s0v = ws[WS_S0 + b * R_ + tid];  // row-independent term
        lo.x += s0v; lo.y += s0v; lo.z += s0v; lo.w += s0v;
        hi.x += s0v; hi.y += s0v; hi.z += s0v; hi.w += s0v;
        p4lo[tid] = lo;
        p4hi[tid] = hi;
    }
    __syncthreads();   // smem[] partials dead; reuse as ep[4][8][64]

    // Epilogue: split-K register-tiled GEMM, 8 rows x 4 h per thread.
    float4 (*ep)[8][64] = (float4 (*)[8][64])smem;   // [kq][row][hq], 32 KB
    const int hq = tid & 63;
    const int kq = tid >> 6;
    const int h0 = hq * 4;

    float4 o[8];
    #pragma unroll
    for (int j = 0; j < 8; ++j) o[j] = make_float4(0.f, 0.f, 0.f, 0.f);
    const int rrb = kq * 32;
    #pragma unroll 4
    for (int i = 0; i < 32; ++i) {
        const int rr = rrb + i;
        const float4 plo = p4lo[rr];                               // broadcast
        const float4 phi = p4hi[rr];                               // broadcast
        const float4 wv4 = *(const float4*)(vW2 + rr * OUT_ + h0); // coalesced
        o[0].x = fmaf(plo.x, wv4.x, o[0].x); o[0].y = fmaf(plo.x, wv4.y, o[0].y);
        o[0].z = fmaf(plo.x, wv4.z, o[0].z); o[0].w = fmaf(plo.x, wv4.w, o[0].w);
        o[1].x = fmaf(plo.y, wv4.x, o[1].x); o[1].y = fmaf(plo.y, wv4.y, o[1].y);
        o[1].z = fmaf(plo.y, wv4.z, o[1].z); o[1].w = fmaf(plo.y, wv4.w, o[1].w);
        o[2].x = fmaf(plo.z, wv4.x, o[2].x); o[2].y = fmaf(plo.z, wv4.y, o[2].y);
        o[2].z = fmaf(plo.z, wv4.z, o[2].z); o[2].w = fmaf(plo.z, wv4.w, o[2].w);
        o[3].x = fmaf(plo.w, wv4.x, o[3].x); o[3].y = fmaf(plo.w, wv4.y, o[3].y);
        o[3].z = fmaf(plo.w, wv4.z, o[3].z); o[3].w = fmaf(plo.w, wv4.w, o[3].w);
        o[4].x = fmaf(phi.x, wv4.x, o[4].x); o[4].y = fmaf(phi.x, wv4.y, o[4].y);
        o[4].z = fmaf(phi.x, wv4.z, o[4].z); o[4].w = fmaf(phi.x, wv4.w, o[4].w);
        o[5].x = fmaf(phi.y, wv4.x, o[5].x); o[5].y = fmaf(phi.y, wv4.y, o[5].y);
        o[5].z = fmaf(phi.y, wv4.z, o[5].z); o[5].w = fmaf(phi.y, wv4.w, o[5].w);
        o[6].x = fmaf(phi.z, wv4.x, o[6].x); o[6].y = fmaf(phi.z, wv4.y, o[6].y);
        o[6].z = fmaf(phi.z, wv4.z, o[6].z); o[6].w = fmaf(phi.z, wv4.w, o[6].w);
        o[7].x = fmaf(phi.w, wv4.x, o[7].x); o[7].y = fmaf(phi.w, wv4.y, o[7].y);
        o[7].z = fmaf(phi.w, wv4.z, o[7].z); o[7].w = fmaf(phi.w, wv4.w, o[7].w);
    }
    #pragma unroll
    for (int j = 0; j < 8; ++j) ep[kq][j][hq] = o[j];
    __syncthreads();

    // final combine: thread = (row = tid>>5, hq2 = tid&31 -> hq2, hq2+32)
    const int row  = tid >> 5;
    const int hqa  = tid & 31;
    float* __restrict__ orow = out + (size_t)(b * 512 + grp * 8) * OUT_ + row * OUT_;
    #pragma unroll
    for (int half = 0; half < 2; ++half) {
        const int hh = hqa + half * 32;
        const float4 e0 = ep[0][row][hh];
        const float4 e1 = ep[1][row][hh];
        const float4 e2 = ep[2][row][hh];
        const float4 e3 = ep[3][row][hh];
        const float4 bias = *(const float4*)(vb2 + hh * 4);
        float4 oo;
        oo.x = e0.x + e1.x + e2.x + e3.x + bias.x;
        oo.y = e0.y + e1.y + e2.y + e3.y + bias.y;
        oo.z = e0.z + e1.z + e2.z + e3.z + bias.z;
        oo.w = e0.w + e1.w + e2.w + e3.w + bias.w;
        *(float4*)(orow + hh * 4) = oo;        // b128 coalesced store
    }
}

extern "C" void kernel_launch(void* const* d_in, const int* in_sizes, int n_in,
                              void* d_out, int out_size, void* d_ws, size_t ws_size,
                              hipStream_t stream) {
    const float* state   = (const float*)d_in[0];   // [B,T,A,C]
    const float* session = (const float*)d_in[1];   // [B,H]
    const float* query   = (const float*)d_in[4];   // [R]
    const float* pos     = (const float*)d_in[5];   // [C,R]
    const float* kW1     = (const float*)d_in[6];   // [R+H, R]
    const float* kb1     = (const float*)d_in[7];   // [R]
    const float* kW2     = (const float*)d_in[8];   // [R, R]
    const float* vW1     = (const float*)d_in[10];  // [R+H+1, R]
    const float* vb1     = (const float*)d_in[11];  // [R]
    const float* vW2     = (const float*)d_in[12];  // [R, OUT]
    const float* vb2     = (const float*)d_in[13];  // [OUT]

    float* ws  = (float*)d_ws;
    float* out = (float*)d_out;

    prep_kernel<<<137, 256, 0, stream>>>(session, query, pos, kW1, kb1, kW2,
                                         vW1, vb1, ws);
    softmax_coef_kernel<<<B_, 1024, 0, stream>>>(vW1, ws);
    main_kernel<<<B_ * 64, 256, 0, stream>>>(state, vW2, vb2, ws, out);
}